// Round 1
// 430.809 us; speedup vs baseline: 1.4068x; 1.4068x over previous
//
#include <hip/hip_runtime.h>
#include <hip/hip_bf16.h>

typedef unsigned short u16;
typedef __attribute__((ext_vector_type(8))) short short8;
typedef __attribute__((ext_vector_type(4))) float floatx4;

#define HWPIX 16384
#define IMG 128

__device__ __forceinline__ float b2f(u16 u) {
    unsigned int x = ((unsigned int)u) << 16;
    return __builtin_bit_cast(float, x);
}
__device__ __forceinline__ u16 f2b(float f) {
    __hip_bfloat16 h = __float2bfloat16(f);
    return __builtin_bit_cast(u16, h);
}

// ---------------------------------------------------------------------------
// conv1x1: out[b][m][p] = act(scale * sum_c W[m][c] * X[c][p] + bias[m])
// IN_WS=1: X bf16 workspace. IN_WS=0: X fp32 (ein0 c<256, ein1 c>=256).
// W/bias fp32; out bf16. Tiles M=64, N=128px, Kc=32. Software-pipelined:
// chunk k+1 global->regs overlaps MFMA on chunk k.
// ---------------------------------------------------------------------------
template<int IN_WS>
__global__ __launch_bounds__(256)
void conv1x1_kernel(const float* __restrict__ ein0, const float* __restrict__ ein1,
                    const u16* __restrict__ bws,
                    const float* __restrict__ w, const float* __restrict__ bias,
                    u16* __restrict__ out, int K, float scale, int relu)
{
    __shared__ u16 Alds[64 * 40];   // [m][k] stride 40
    __shared__ u16 Blds[128 * 40];  // [p][k]

    const int tid = threadIdx.x;
    const int wave = tid >> 6, lane = tid & 63;
    const int quad = lane >> 4, l16 = lane & 15;
    const int pbase = blockIdx.x * 128;
    const int mbase = blockIdx.y * 64;
    const int b = blockIdx.z;

    floatx4 acc[8];
#pragma unroll
    for (int f = 0; f < 8; ++f) acc[f] = (floatx4){0.f, 0.f, 0.f, 0.f};

    const int a_r = tid >> 2, a_kg = tid & 3;       // A: 64 rows x 4 kgroups(8)
    const int b_c4 = (tid & 7) * 4;                 // B: 8 ch-groups of 4
    const int b_p4 = (tid >> 3) * 4;                // B: 32 px-groups of 4

    // prefetch registers
    float4 af0, af1;
    float4 bfl[4];       // fp32 path: [ch_i] -> 4 px
    uint2  bbl[4];       // bf16 path: [ch_i] -> 4 px (4 u16)

    auto load_chunk = [&](int kc) {
        const int c0 = kc * 32;
        const float* wp = w + (size_t)(mbase + a_r) * K + c0 + a_kg * 8;
        af0 = *(const float4*)wp;
        af1 = *(const float4*)(wp + 4);
        if (IN_WS) {
#pragma unroll
            for (int i = 0; i < 4; ++i) {
                const u16* s = bws + ((size_t)b * 256 + c0 + b_c4 + i) * HWPIX + pbase + b_p4;
                bbl[i] = *(const uint2*)s;
            }
        } else {
            const float* base = (c0 < 256) ? ein0 : ein1;
            const int cb = c0 & 255;
#pragma unroll
            for (int i = 0; i < 4; ++i) {
                const float* s = base + ((size_t)b * 256 + cb + b_c4 + i) * HWPIX + pbase + b_p4;
                bfl[i] = *(const float4*)s;
            }
        }
    };
    auto write_chunk = [&]() {
        union { uint4 v; u16 s[8]; } ta;
        ta.s[0] = f2b(af0.x); ta.s[1] = f2b(af0.y); ta.s[2] = f2b(af0.z); ta.s[3] = f2b(af0.w);
        ta.s[4] = f2b(af1.x); ta.s[5] = f2b(af1.y); ta.s[6] = f2b(af1.z); ta.s[7] = f2b(af1.w);
        *(uint4*)&Alds[a_r * 40 + a_kg * 8] = ta.v;
        if (IN_WS) {
            union { uint2 v; u16 s[4]; } c[4];
#pragma unroll
            for (int i = 0; i < 4; ++i) c[i].v = bbl[i];
#pragma unroll
            for (int j = 0; j < 4; ++j) {
                union { uint2 v; u16 s[4]; } o;
#pragma unroll
                for (int i = 0; i < 4; ++i) o.s[i] = c[i].s[j];
                *(uint2*)&Blds[(b_p4 + j) * 40 + b_c4] = o.v;
            }
        } else {
            float px[4][4];
#pragma unroll
            for (int i = 0; i < 4; ++i) {
                px[i][0] = bfl[i].x; px[i][1] = bfl[i].y; px[i][2] = bfl[i].z; px[i][3] = bfl[i].w;
            }
#pragma unroll
            for (int j = 0; j < 4; ++j) {
                union { uint2 v; u16 s[4]; } o;
#pragma unroll
                for (int i = 0; i < 4; ++i) o.s[i] = f2b(px[i][j]);
                *(uint2*)&Blds[(b_p4 + j) * 40 + b_c4] = o.v;
            }
        }
    };

    const int nchunk = K >> 5;
    load_chunk(0);
    for (int kc = 0; kc < nchunk; ++kc) {
        if (kc) __syncthreads();           // prev MFMA done reading LDS
        write_chunk();
        __syncthreads();
        if (kc + 1 < nchunk) load_chunk(kc + 1);   // overlaps MFMA below
        short8 afrag = *(const short8*)&Alds[(wave * 16 + l16) * 40 + quad * 8];
#pragma unroll
        for (int f = 0; f < 8; ++f) {
            short8 bfrag = *(const short8*)&Blds[(f * 16 + l16) * 40 + quad * 8];
            acc[f] = __builtin_amdgcn_mfma_f32_16x16x32_bf16(afrag, bfrag, acc[f], 0, 0, 0);
        }
    }

    // epilogue: D[row=quad*4+r][col=l16]
    float bv[4];
#pragma unroll
    for (int r = 0; r < 4; ++r) {
        int m = mbase + wave * 16 + quad * 4 + r;
        bv[r] = bias ? bias[m] : 0.f;
    }
#pragma unroll
    for (int f = 0; f < 8; ++f) {
        int p = pbase + f * 16 + l16;
#pragma unroll
        for (int r = 0; r < 4; ++r) {
            int m = mbase + wave * 16 + quad * 4 + r;
            float v = acc[f][r] * scale + bv[r];
            if (relu) v = fmaxf(v, 0.f);
            out[((size_t)b * 256 + m) * HWPIX + p] = f2b(v);
        }
    }
}

// ---------------------------------------------------------------------------
// attention: one workgroup per (b, bh, bw, head). Q 64x64, K/V 196x64 (pad 224)
// Staging v2: row-segment vectorized loads (uint2 x4 per (ch,window-row)),
// ALL global loads issued before any wait (single latency exposure), ch-major
// lane mapping so LDS writes are ~conflict-free. XCD-contiguous block swizzle
// keeps halo reuse inside one L2.
// ---------------------------------------------------------------------------
__global__ __launch_bounds__(256)
void attn_kernel(const u16* __restrict__ qmap, const u16* __restrict__ kmap,
                 const u16* __restrict__ vmap, const float* __restrict__ relh,
                 const float* __restrict__ relw, float* __restrict__ out)
{
    __shared__ u16 Qlds[64 * 72];    // [qpos][dd]; reused as O[dd][qpos]
    __shared__ u16 Klds[224 * 72];   // [kpos][dd]; reused as S[qpos][232]
    __shared__ u16 Vlds[64 * 232];   // V^T: [dd][kpos]
    __shared__ float RelHf[448], RelWf[448];

    const int tid = threadIdx.x;
    const int wave = tid >> 6, lane = tid & 63;
    const int quad = lane >> 4, l16 = lane & 15;

    // XCD-contiguous swizzle: each XCD (= linear wgid % 8) owns 512 consecutive
    // logical blocks = two full (b,head) 16x16 planes -> halo L2 reuse.
    const int n = blockIdx.x + 16 * blockIdx.y + 256 * blockIdx.z;
    const int n2 = (n & 7) * 512 + (n >> 3);
    const int bw = n2 & 15, bh = (n2 >> 4) & 15;
    const int head = (n2 >> 8) & 3, b = n2 >> 10;

    const size_t chbase = ((size_t)b * 256 + head * 64) * HWPIX;

    // ================= phase 0: issue ALL global loads (no waits) ==========
    // rel tables (issued first so their drain doesn't drain K/V)
    float rh0 = relh[tid], rw0 = relw[tid];
    float rh1 = 0.f, rw1 = 0.f;
    if (tid < 192) { rh1 = relh[tid + 256]; rw1 = relw[tid + 256]; }

    // Q: lane=ch, wave=row pair (rows wave, wave+4); 2x uint4 per thread
    const u16* qrow = qmap + chbase + (size_t)lane * HWPIX + bw * 8;
    uint4 q0 = *(const uint4*)(qrow + (bh * 8 + wave) * IMG);
    uint4 q1 = *(const uint4*)(qrow + (bh * 8 + wave + 4) * IMG);

    // K/V row segments: lane=ch (0..63), slots s -> window row wr=wave+4s.
    // 16-col aligned-ish span (4x uint2 at 8B align) covering the 14 needed.
    const int cbyte = min(max(bw * 16 - 8, 0), 224);  // 2*cb, cb=clamp(8bw-4,0,112)
    uint2 kseg[4][4], vseg[4][4];
#pragma unroll
    for (int s = 0; s < 4; ++s) {
        if (s < 3 || wave < 2) {                      // wr < 14 (wave-uniform)
            const int wr = wave + 4 * s;
            const int ih = bh * 8 - 3 + wr;
            const int ihc = min(max(ih, 0), 127);
            const char* kp = (const char*)(kmap + chbase + (size_t)lane * HWPIX) + ihc * 256 + cbyte;
            const char* vp = (const char*)(vmap + chbase + (size_t)lane * HWPIX) + ihc * 256 + cbyte;
#pragma unroll
            for (int j = 0; j < 4; ++j) {
                kseg[s][j] = *(const uint2*)(kp + 8 * j);
                vseg[s][j] = *(const uint2*)(vp + 8 * j);
            }
        }
    }

    // ================= phase 1: rel + Q -> LDS =============================
    RelHf[tid] = rh0; RelWf[tid] = rw0;
    if (tid < 192) { RelHf[tid + 256] = rh1; RelWf[tid + 256] = rw1; }
    {
        union { uint4 v; u16 s[8]; } t0, t1;
        t0.v = q0; t1.v = q1;
#pragma unroll
        for (int i = 0; i < 8; ++i) {   // lanes span ch 0..63 -> 2-way banks (free)
            Qlds[(wave * 8 + i) * 72 + lane] = t0.s[i];
            Qlds[((wave + 4) * 8 + i) * 72 + lane] = t1.s[i];
        }
    }
    __syncthreads();   // RelHf/RelWf visible before K writes read them

    // ================= phase 2: K(+rel), V^T -> LDS; pad ===================
    const int iwb = bw * 8 - 3;
#pragma unroll
    for (int s = 0; s < 4; ++s) {
        if (s < 3 || wave < 2) {
            const int wr = wave + 4 * s;
            const int ih = bh * 8 - 3 + wr;
            const bool rok = (unsigned)ih < 128u;
            union { uint2 v[4]; u16 u[16]; } kr, vr;
#pragma unroll
            for (int j = 0; j < 4; ++j) { kr.v[j] = kseg[s][j]; vr.v[j] = vseg[s][j]; }
            // edge column realignment (wave-uniform branch, static indices):
            // want kr.u[sc+1] == column iwb+sc
            if (bw == 0) {
#pragma unroll
                for (int i = 15; i >= 4; --i) { kr.u[i] = kr.u[i - 4]; vr.u[i] = vr.u[i - 4]; }
            } else if (bw == 15) {
#pragma unroll
                for (int i = 0; i < 12; ++i) { kr.u[i] = kr.u[i + 4]; vr.u[i] = vr.u[i + 4]; }
            }
            const int kb = wr * 14;
            u16 vm[14];
#pragma unroll
            for (int sc = 0; sc < 14; ++sc) {
                const bool ok = rok && ((unsigned)(iwb + sc) < 128u);
                vm[sc] = ok ? vr.u[sc + 1] : (u16)0;
                const float kv = ok ? b2f(kr.u[sc + 1]) : 0.f;  // pad gets rel only (matches ref)
                const float rel = (lane < 32) ? RelHf[wr * 32 + (lane & 31)]
                                              : RelWf[sc * 32 + (lane & 31)];
                // lanes span ch 0..63 at fixed kpos -> 2-way banks (free)
                Klds[(kb + sc) * 72 + lane] = f2b(kv + rel);
            }
            unsigned* vrow = (unsigned*)&Vlds[lane * 232 + kb];   // contiguous 14 u16
#pragma unroll
            for (int p = 0; p < 7; ++p)
                vrow[p] = (unsigned)vm[2 * p] | ((unsigned)vm[2 * p + 1] << 16);
        }
    }
    // zero-pad kpos 196..223 (V must be 0 so attn 0 * pad != NaN)
    for (int t = tid; t < 28 * 64; t += 256) {
        int kp_ = 196 + (t >> 6), ch = t & 63;
        Klds[kp_ * 72 + ch] = 0;
        Vlds[ch * 232 + kp_] = 0;
    }
    __syncthreads();

    // ---- sim = Q K^T : wave strip 16(qpos) x 224(kpos)
    floatx4 sacc[14];
#pragma unroll
    for (int f = 0; f < 14; ++f) sacc[f] = (floatx4){0.f, 0.f, 0.f, 0.f};
    __builtin_amdgcn_s_setprio(1);
#pragma unroll
    for (int kc = 0; kc < 2; ++kc) {
        short8 qa = *(const short8*)&Qlds[(wave * 16 + l16) * 72 + kc * 32 + quad * 8];
#pragma unroll
        for (int f = 0; f < 14; ++f) {
            short8 kb = *(const short8*)&Klds[(f * 16 + l16) * 72 + kc * 32 + quad * 8];
            sacc[f] = __builtin_amdgcn_mfma_f32_16x16x32_bf16(qa, kb, sacc[f], 0, 0, 0);
        }
    }
    __builtin_amdgcn_s_setprio(0);

    // ---- softmax over kpos; row = quad*4+r
    float pm[14][4], rmax[4], rsum[4];
#pragma unroll
    for (int r = 0; r < 4; ++r) rmax[r] = -3.0e4f;
#pragma unroll
    for (int f = 0; f < 14; ++f) {
        int col = f * 16 + l16;
#pragma unroll
        for (int r = 0; r < 4; ++r) {
            float v = (col < 196) ? sacc[f][r] : -3.0e4f;
            pm[f][r] = v;
            rmax[r] = fmaxf(rmax[r], v);
        }
    }
#pragma unroll
    for (int off = 1; off < 16; off <<= 1)
#pragma unroll
        for (int r = 0; r < 4; ++r)
            rmax[r] = fmaxf(rmax[r], __shfl_xor(rmax[r], off, 64));
#pragma unroll
    for (int r = 0; r < 4; ++r) rsum[r] = 0.f;
#pragma unroll
    for (int f = 0; f < 14; ++f)
#pragma unroll
        for (int r = 0; r < 4; ++r) {
            float e = __expf(pm[f][r] - rmax[r]);
            pm[f][r] = e;
            rsum[r] += e;
        }
#pragma unroll
    for (int off = 1; off < 16; off <<= 1)
#pragma unroll
        for (int r = 0; r < 4; ++r)
            rsum[r] += __shfl_xor(rsum[r], off, 64);
    float rinv[4];
#pragma unroll
    for (int r = 0; r < 4; ++r) rinv[r] = 1.f / rsum[r];

    __syncthreads();  // all waves done reading Qlds/Klds

    // ---- P (bf16) into S = Klds region, [qpos][232]
    u16* S = Klds;
#pragma unroll
    for (int f = 0; f < 14; ++f)
#pragma unroll
        for (int r = 0; r < 4; ++r)
            S[(wave * 16 + quad * 4 + r) * 232 + f * 16 + l16] = f2b(pm[f][r] * rinv[r]);
    __syncthreads();

    // ---- out = P V : wave strip 16(qpos) x 64(dd), K = 224
    floatx4 oacc[4];
#pragma unroll
    for (int f = 0; f < 4; ++f) oacc[f] = (floatx4){0.f, 0.f, 0.f, 0.f};
    __builtin_amdgcn_s_setprio(1);
#pragma unroll
    for (int kc = 0; kc < 7; ++kc) {
        short8 pa = *(const short8*)&S[(wave * 16 + l16) * 232 + kc * 32 + quad * 8];
#pragma unroll
        for (int f = 0; f < 4; ++f) {
            short8 vb = *(const short8*)&Vlds[(f * 16 + l16) * 232 + kc * 32 + quad * 8];
            oacc[f] = __builtin_amdgcn_mfma_f32_16x16x32_bf16(pa, vb, oacc[f], 0, 0, 0);
        }
    }
    __builtin_amdgcn_s_setprio(0);

    // ---- transpose O through Qlds region (O[dd][qpos], stride 72)
    u16* O = Qlds;
#pragma unroll
    for (int f = 0; f < 4; ++f)
#pragma unroll
        for (int r = 0; r < 4; ++r)
            O[(f * 16 + l16) * 72 + wave * 16 + quad * 4 + r] = f2b(oacc[f][r]);
    __syncthreads();

    // ---- fp32 output stores
    for (int t = tid; t < 512; t += 256) {
        int ch = t >> 3, r = t & 7;
        const u16* src = &O[ch * 72 + r * 8];
        float4 v0 = {b2f(src[0]), b2f(src[1]), b2f(src[2]), b2f(src[3])};
        float4 v1 = {b2f(src[4]), b2f(src[5]), b2f(src[6]), b2f(src[7])};
        float* dst = out + chbase + ch * HWPIX + (bh * 8 + r) * IMG + bw * 8;
        *(float4*)dst = v0;
        *(float4*)(dst + 4) = v1;
    }
}

extern "C" void kernel_launch(void* const* d_in, const int* in_sizes, int n_in,
                              void* d_out, int out_size, void* d_ws, size_t ws_size,
                              hipStream_t stream)
{
    (void)in_sizes; (void)n_in; (void)out_size; (void)ws_size;
    const float* noisy = (const float*)d_in[0];
    const float* aux   = (const float*)d_in[1];
    const float* w_map = (const float*)d_in[2];
    const float* b_map = (const float*)d_in[3];
    const float* w_q   = (const float*)d_in[4];
    const float* w_k   = (const float*)d_in[5];
    const float* w_v   = (const float*)d_in[6];
    const float* rel_h = (const float*)d_in[7];
    const float* rel_w = (const float*)d_in[8];
    float* out = (float*)d_out;

    // ws layout (96 MiB): [nv(naux->vmap) 32MiB][kmap 32MiB][qmap 32MiB]
    u16* nv   = (u16*)d_ws;
    u16* kmap = nv   + (size_t)16777216;
    u16* qmap = kmap + (size_t)16777216;

    dim3 cgrid(128, 4, 4);  // pixel tiles, m tiles, batch
    conv1x1_kernel<0><<<cgrid, 256, 0, stream>>>(noisy, aux, nullptr, w_map, b_map, nv,   512, 1.f,    1);
    conv1x1_kernel<1><<<cgrid, 256, 0, stream>>>(nullptr, nullptr, nv, w_q,  nullptr, qmap, 256, 0.125f, 0);
    conv1x1_kernel<1><<<cgrid, 256, 0, stream>>>(nullptr, nullptr, nv, w_k,  nullptr, kmap, 256, 1.f,    0);
    conv1x1_kernel<0><<<cgrid, 256, 0, stream>>>(noisy, noisy, nullptr, w_v, nullptr, nv,   256, 1.f,    0);
    attn_kernel<<<dim3(16, 16, 16), 256, 0, stream>>>(qmap, kmap, nv, rel_h, rel_w, out);
}

// Round 3
// 413.507 us; speedup vs baseline: 1.4657x; 1.0418x over previous
//
#include <hip/hip_runtime.h>
#include <hip/hip_bf16.h>

typedef unsigned short u16;
typedef __attribute__((ext_vector_type(8))) short short8;
typedef __attribute__((ext_vector_type(4))) float floatx4;

#define HWPIX 16384
#define IMG 128

__device__ __forceinline__ float b2f(u16 u) {
    unsigned int x = ((unsigned int)u) << 16;
    return __builtin_bit_cast(float, x);
}
__device__ __forceinline__ u16 f2b(float f) {
    __hip_bfloat16 h = __float2bfloat16(f);
    return __builtin_bit_cast(u16, h);
}

// bf16 weight cache: [wmap 131072][wk 65536][wq 65536][wv 65536]
__device__ __align__(16) u16 g_w16[327680];

__global__ __launch_bounds__(256)
void wconv_kernel(const float* __restrict__ wmap, const float* __restrict__ wq,
                  const float* __restrict__ wk, const float* __restrict__ wv)
{
    int i = blockIdx.x * 256 + threadIdx.x;
    const float* src; int off;
    if (i < 131072)      { src = wmap; off = i; }
    else if (i < 196608) { src = wk;   off = i - 131072; }
    else if (i < 262144) { src = wq;   off = i - 196608; }
    else                 { src = wv;   off = i - 262144; }
    g_w16[i] = f2b(src[off]);
}

// ---------------------------------------------------------------------------
// conv1x1 v2: out[b][m][p] = act(scale * sum_c W[m][c] * X[c][p] + bias[m])
// BM=128, BN=128px, BK=64; 4 waves, each 64m x 64px (acc 4x4 frags).
// 32 MFMA per barrier-pair. Weights bf16 (g_w16).
// IN_WS=1: X bf16 ws. IN_WS=0: X fp32 (ein0 c<256, ein1 c>=256).
// blockIdx.y>=2 -> outB/scaleB (fused k|q conv, M=512 stacked [wk;wq]).
// ---------------------------------------------------------------------------
template<int IN_WS>
__global__ __launch_bounds__(256)
void conv2_kernel(const float* __restrict__ ein0, const float* __restrict__ ein1,
                  const u16* __restrict__ bws, int woff,
                  const float* __restrict__ bias,
                  u16* __restrict__ outA, u16* __restrict__ outB,
                  int K, float scaleA, float scaleB, int relu)
{
    __shared__ u16 Alds[128 * 72];   // [m][k] stride 72 (144B rows, 16B-aligned)
    __shared__ u16 Blds[128 * 72];   // [px][k]

    const int tid = threadIdx.x;
    const int wave = tid >> 6, lane = tid & 63;
    const int quad = lane >> 4, l16 = lane & 15;
    const int wmo = (wave >> 1) * 64;   // wave m offset
    const int wpo = (wave & 1) * 64;    // wave px offset
    const int pbase = blockIdx.x * 128;
    const int mbase = blockIdx.y * 128;
    const int b = blockIdx.z;
    u16* out = (blockIdx.y >= 2) ? outB : outA;
    const float scale = (blockIdx.y >= 2) ? scaleB : scaleA;
    const int mb = mbase & 255;
    const u16* wsrc = g_w16 + woff;

    floatx4 acc[4][4];
#pragma unroll
    for (int mi = 0; mi < 4; ++mi)
#pragma unroll
        for (int pj = 0; pj < 4; ++pj) acc[mi][pj] = (floatx4){0.f, 0.f, 0.f, 0.f};

    const int a_r = tid >> 1, a_s = (tid & 1) * 32;   // A: 128 rows x 2 seg(32)
    const int b_c = (tid & 15) * 4;                   // B: 16 ch-groups of 4
    const int b_p = (tid >> 4) * 8;                   // B: 16 px-groups of 8

    uint4  apre[4];
    uint4  bpre[4];       // bf16 path: [ch_i] -> 8 px
    float4 fpre[4][2];    // fp32 path: [ch_i] -> 8 px

    auto load_chunk = [&](int kc) {
        const int c0 = kc * 64;
        const u16* wp = wsrc + (size_t)(mbase + a_r) * K + c0 + a_s;
#pragma unroll
        for (int j = 0; j < 4; ++j) apre[j] = *(const uint4*)(wp + j * 8);
        if (IN_WS) {
#pragma unroll
            for (int i = 0; i < 4; ++i)
                bpre[i] = *(const uint4*)(bws + ((size_t)b * 256 + c0 + b_c + i) * HWPIX + pbase + b_p);
        } else {
            const float* base = (c0 < 256) ? ein0 : ein1;
            const int cb = c0 & 255;
#pragma unroll
            for (int i = 0; i < 4; ++i) {
                const float* s = base + ((size_t)b * 256 + cb + b_c + i) * HWPIX + pbase + b_p;
                fpre[i][0] = *(const float4*)s;
                fpre[i][1] = *(const float4*)(s + 4);
            }
        }
    };
    auto write_chunk = [&]() {
#pragma unroll
        for (int j = 0; j < 4; ++j)
            *(uint4*)&Alds[a_r * 72 + a_s + j * 8] = apre[j];
        if (IN_WS) {
            union { uint4 v; u16 s[8]; } c[4];
#pragma unroll
            for (int i = 0; i < 4; ++i) c[i].v = bpre[i];
#pragma unroll
            for (int j = 0; j < 8; ++j) {
                union { uint2 v; u16 s[4]; } o;
#pragma unroll
                for (int i = 0; i < 4; ++i) o.s[i] = c[i].s[j];
                *(uint2*)&Blds[(b_p + j) * 72 + b_c] = o.v;
            }
        } else {
            float px[4][8];
#pragma unroll
            for (int i = 0; i < 4; ++i) {
                px[i][0] = fpre[i][0].x; px[i][1] = fpre[i][0].y;
                px[i][2] = fpre[i][0].z; px[i][3] = fpre[i][0].w;
                px[i][4] = fpre[i][1].x; px[i][5] = fpre[i][1].y;
                px[i][6] = fpre[i][1].z; px[i][7] = fpre[i][1].w;
            }
#pragma unroll
            for (int j = 0; j < 8; ++j) {
                union { uint2 v; u16 s[4]; } o;
#pragma unroll
                for (int i = 0; i < 4; ++i) o.s[i] = f2b(px[i][j]);
                *(uint2*)&Blds[(b_p + j) * 72 + b_c] = o.v;
            }
        }
    };

    const int nchunk = K >> 6;
    load_chunk(0);
    for (int kc = 0; kc < nchunk; ++kc) {
        if (kc) __syncthreads();           // prev MFMA done reading LDS
        write_chunk();
        __syncthreads();
        if (kc + 1 < nchunk) load_chunk(kc + 1);   // overlaps MFMA below
#pragma unroll
        for (int k2 = 0; k2 < 2; ++k2) {
            short8 af[4];
#pragma unroll
            for (int mi = 0; mi < 4; ++mi)
                af[mi] = *(const short8*)&Alds[(wmo + mi * 16 + l16) * 72 + k2 * 32 + quad * 8];
#pragma unroll
            for (int pj = 0; pj < 4; ++pj) {
                short8 bf_ = *(const short8*)&Blds[(wpo + pj * 16 + l16) * 72 + k2 * 32 + quad * 8];
#pragma unroll
                for (int mi = 0; mi < 4; ++mi)
                    acc[mi][pj] = __builtin_amdgcn_mfma_f32_16x16x32_bf16(af[mi], bf_, acc[mi][pj], 0, 0, 0);
            }
        }
    }

    // epilogue: D[row=quad*4+r][col=l16]
    float bv[4][4];
#pragma unroll
    for (int mi = 0; mi < 4; ++mi)
#pragma unroll
        for (int r = 0; r < 4; ++r)
            bv[mi][r] = bias ? bias[mb + wmo + mi * 16 + quad * 4 + r] : 0.f;
#pragma unroll
    for (int mi = 0; mi < 4; ++mi)
#pragma unroll
        for (int pj = 0; pj < 4; ++pj)
#pragma unroll
            for (int r = 0; r < 4; ++r) {
                float v = acc[mi][pj][r] * scale + bv[mi][r];
                if (relu) v = fmaxf(v, 0.f);
                out[((size_t)b * 256 + mb + wmo + mi * 16 + quad * 4 + r) * HWPIX
                    + pbase + wpo + pj * 16 + l16] = f2b(v);
            }
}

// V^T LDS swizzle v2. Row stride 512B (multiple of 128B so the XOR is a
// bijection WITHIN the row: colByte<512, XOR touches bits 4-8 only).
// key = dd&31 -> PV b128 reads: 16 lanes hit 16 distinct 16B slots (2-way,
// free); V dword writes: 64 lanes -> 32 slots (2-way, free).
__device__ __forceinline__ int vswz(int dd, int colByte) {
    return dd * 512 + (colByte ^ ((dd & 31) << 4));
}

// ---------------------------------------------------------------------------
// attention: one workgroup per (b, bh, bw, head). Q 64x64, K/V 196x64 (pad 224)
// ---------------------------------------------------------------------------
__global__ __launch_bounds__(256)
void attn_kernel(const u16* __restrict__ qmap, const u16* __restrict__ kmap,
                 const u16* __restrict__ vmap, const float* __restrict__ relh,
                 const float* __restrict__ relw, float* __restrict__ out)
{
    __shared__ u16 Qlds[64 * 72];    // [qpos][dd]; reused as O[dd][qpos]
    __shared__ u16 Klds[224 * 72];   // [kpos][dd]; reused as S[qpos][232]
    __shared__ u16 Vlds[64 * 256];   // V^T: [dd][kpos], XOR-swizzled (vswz)
    __shared__ float RelHf[448], RelWf[448];

    const int tid = threadIdx.x;
    const int wave = tid >> 6, lane = tid & 63;
    const int quad = lane >> 4, l16 = lane & 15;
    char* Vb = (char*)Vlds;

    // XCD-contiguous swizzle: each XCD owns 512 consecutive logical blocks
    // = two full (b,head) 16x16 planes -> halo L2 reuse.
    const int n = blockIdx.x + 16 * blockIdx.y + 256 * blockIdx.z;
    const int n2 = (n & 7) * 512 + (n >> 3);
    const int bw = n2 & 15, bh = (n2 >> 4) & 15;
    const int head = (n2 >> 8) & 3, b = n2 >> 10;

    const size_t chbase = ((size_t)b * 256 + head * 64) * HWPIX;

    // ================= phase 0: issue ALL global loads (no waits) ==========
    float rh0 = relh[tid], rw0 = relw[tid];
    float rh1 = 0.f, rw1 = 0.f;
    if (tid < 192) { rh1 = relh[tid + 256]; rw1 = relw[tid + 256]; }

    // Q: lane=ch, wave=row pair (rows wave, wave+4); 2x uint4 per thread
    const u16* qrow = qmap + chbase + (size_t)lane * HWPIX + bw * 8;
    uint4 q0 = *(const uint4*)(qrow + (bh * 8 + wave) * IMG);
    uint4 q1 = *(const uint4*)(qrow + (bh * 8 + wave + 4) * IMG);

    // K/V row segments: lane=ch (0..63), slots s -> window row wr=wave+4s.
    const int cbyte = min(max(bw * 16 - 8, 0), 224);  // 2*cb, cb=clamp(8bw-4,0,112)
    uint2 kseg[4][4], vseg[4][4];
#pragma unroll
    for (int s = 0; s < 4; ++s) {
        if (s < 3 || wave < 2) {                      // wr < 14 (wave-uniform)
            const int wr = wave + 4 * s;
            const int ih = bh * 8 - 3 + wr;
            const int ihc = min(max(ih, 0), 127);
            const char* kp = (const char*)(kmap + chbase + (size_t)lane * HWPIX) + ihc * 256 + cbyte;
            const char* vp = (const char*)(vmap + chbase + (size_t)lane * HWPIX) + ihc * 256 + cbyte;
#pragma unroll
            for (int j = 0; j < 4; ++j) {
                kseg[s][j] = *(const uint2*)(kp + 8 * j);
                vseg[s][j] = *(const uint2*)(vp + 8 * j);
            }
        }
    }

    // ================= phase 1: rel + Q -> LDS =============================
    RelHf[tid] = rh0; RelWf[tid] = rw0;
    if (tid < 192) { RelHf[tid + 256] = rh1; RelWf[tid + 256] = rw1; }
    {
        union { uint4 v; u16 s[8]; } t0, t1;
        t0.v = q0; t1.v = q1;
#pragma unroll
        for (int i = 0; i < 8; ++i) {   // lanes span ch 0..63 -> 2-way banks (free)
            Qlds[(wave * 8 + i) * 72 + lane] = t0.s[i];
            Qlds[((wave + 4) * 8 + i) * 72 + lane] = t1.s[i];
        }
    }
    __syncthreads();   // RelHf/RelWf visible before K writes read them

    // ================= phase 2: K(+rel), V^T -> LDS; pad ===================
    const int iwb = bw * 8 - 3;
#pragma unroll
    for (int s = 0; s < 4; ++s) {
        if (s < 3 || wave < 2) {
            const int wr = wave + 4 * s;
            const int ih = bh * 8 - 3 + wr;
            const bool rok = (unsigned)ih < 128u;
            union { uint2 v[4]; u16 u[16]; } kr, vr;
#pragma unroll
            for (int j = 0; j < 4; ++j) { kr.v[j] = kseg[s][j]; vr.v[j] = vseg[s][j]; }
            // edge column realignment (wave-uniform branch, static indices):
            // want kr.u[sc+1] == column iwb+sc
            if (bw == 0) {
#pragma unroll
                for (int i = 15; i >= 4; --i) { kr.u[i] = kr.u[i - 4]; vr.u[i] = vr.u[i - 4]; }
            } else if (bw == 15) {
#pragma unroll
                for (int i = 0; i < 12; ++i) { kr.u[i] = kr.u[i + 4]; vr.u[i] = vr.u[i + 4]; }
            }
            const int kb = wr * 14;
            u16 vm[14];
#pragma unroll
            for (int sc = 0; sc < 14; ++sc) {
                const bool ok = rok && ((unsigned)(iwb + sc) < 128u);
                vm[sc] = ok ? vr.u[sc + 1] : (u16)0;
                const float kv = ok ? b2f(kr.u[sc + 1]) : 0.f;  // pad gets rel only (matches ref)
                const float rel = (lane < 32) ? RelHf[wr * 32 + (lane & 31)]
                                              : RelWf[sc * 32 + (lane & 31)];
                Klds[(kb + sc) * 72 + lane] = f2b(kv + rel);
            }
#pragma unroll
            for (int p = 0; p < 7; ++p)
                *(unsigned*)(Vb + vswz(lane, kb * 2 + p * 4)) =
                    (unsigned)vm[2 * p] | ((unsigned)vm[2 * p + 1] << 16);
        }
    }
    // zero-pad kpos 196..223 (V must be 0 so attn 0 * pad != NaN)
    for (int t = tid; t < 28 * 64; t += 256) {
        int kp_ = 196 + (t >> 6), ch = t & 63;
        Klds[kp_ * 72 + ch] = 0;
        *(u16*)(Vb + vswz(ch, kp_ * 2)) = 0;
    }
    __syncthreads();

    // ---- sim = Q K^T : wave strip 16(qpos) x 224(kpos)
    floatx4 sacc[14];
#pragma unroll
    for (int f = 0; f < 14; ++f) sacc[f] = (floatx4){0.f, 0.f, 0.f, 0.f};
    __builtin_amdgcn_s_setprio(1);
#pragma unroll
    for (int kc = 0; kc < 2; ++kc) {
        short8 qa = *(const short8*)&Qlds[(wave * 16 + l16) * 72 + kc * 32 + quad * 8];
#pragma unroll
        for (int f = 0; f < 14; ++f) {
            short8 kb = *(const short8*)&Klds[(f * 16 + l16) * 72 + kc * 32 + quad * 8];
            sacc[f] = __builtin_amdgcn_mfma_f32_16x16x32_bf16(qa, kb, sacc[f], 0, 0, 0);
        }
    }
    __builtin_amdgcn_s_setprio(0);

    // ---- softmax over kpos; row = quad*4+r
    float pm[14][4], rmax[4], rsum[4];
#pragma unroll
    for (int r = 0; r < 4; ++r) rmax[r] = -3.0e4f;
#pragma unroll
    for (int f = 0; f < 14; ++f) {
        int col = f * 16 + l16;
#pragma unroll
        for (int r = 0; r < 4; ++r) {
            float v = (col < 196) ? sacc[f][r] : -3.0e4f;
            pm[f][r] = v;
            rmax[r] = fmaxf(rmax[r], v);
        }
    }
#pragma unroll
    for (int off = 1; off < 16; off <<= 1)
#pragma unroll
        for (int r = 0; r < 4; ++r)
            rmax[r] = fmaxf(rmax[r], __shfl_xor(rmax[r], off, 64));
#pragma unroll
    for (int r = 0; r < 4; ++r) rsum[r] = 0.f;
#pragma unroll
    for (int f = 0; f < 14; ++f)
#pragma unroll
        for (int r = 0; r < 4; ++r) {
            float e = __expf(pm[f][r] - rmax[r]);
            pm[f][r] = e;
            rsum[r] += e;
        }
#pragma unroll
    for (int off = 1; off < 16; off <<= 1)
#pragma unroll
        for (int r = 0; r < 4; ++r)
            rsum[r] += __shfl_xor(rsum[r], off, 64);
    float rinv[4];
#pragma unroll
    for (int r = 0; r < 4; ++r) rinv[r] = 1.f / rsum[r];

    __syncthreads();  // all waves done reading Qlds/Klds

    // ---- P (bf16) into S = Klds region, [qpos][232]
    u16* S = Klds;
#pragma unroll
    for (int f = 0; f < 14; ++f)
#pragma unroll
        for (int r = 0; r < 4; ++r)
            S[(wave * 16 + quad * 4 + r) * 232 + f * 16 + l16] = f2b(pm[f][r] * rinv[r]);
    __syncthreads();

    // ---- out = P V : wave strip 16(qpos) x 64(dd), K = 224
    floatx4 oacc[4];
#pragma unroll
    for (int f = 0; f < 4; ++f) oacc[f] = (floatx4){0.f, 0.f, 0.f, 0.f};
    __builtin_amdgcn_s_setprio(1);
#pragma unroll
    for (int kc = 0; kc < 7; ++kc) {
        short8 pa = *(const short8*)&S[(wave * 16 + l16) * 232 + kc * 32 + quad * 8];
#pragma unroll
        for (int f = 0; f < 4; ++f) {
            short8 vb = *(const short8*)(Vb + vswz(f * 16 + l16, kc * 64 + quad * 16));
            oacc[f] = __builtin_amdgcn_mfma_f32_16x16x32_bf16(pa, vb, oacc[f], 0, 0, 0);
        }
    }
    __builtin_amdgcn_s_setprio(0);

    // ---- transpose O through Qlds region (O[dd][qpos], stride 72)
    u16* O = Qlds;
#pragma unroll
    for (int f = 0; f < 4; ++f)
#pragma unroll
        for (int r = 0; r < 4; ++r)
            O[(f * 16 + l16) * 72 + wave * 16 + quad * 4 + r] = f2b(oacc[f][r]);
    __syncthreads();

    // ---- fp32 output stores
    for (int t = tid; t < 512; t += 256) {
        int ch = t >> 3, r = t & 7;
        const u16* src = &O[ch * 72 + r * 8];
        float4 v0 = {b2f(src[0]), b2f(src[1]), b2f(src[2]), b2f(src[3])};
        float4 v1 = {b2f(src[4]), b2f(src[5]), b2f(src[6]), b2f(src[7])};
        float* dst = out + chbase + ch * HWPIX + (bh * 8 + r) * IMG + bw * 8;
        *(float4*)dst = v0;
        *(float4*)(dst + 4) = v1;
    }
}

extern "C" void kernel_launch(void* const* d_in, const int* in_sizes, int n_in,
                              void* d_out, int out_size, void* d_ws, size_t ws_size,
                              hipStream_t stream)
{
    (void)in_sizes; (void)n_in; (void)out_size; (void)ws_size;
    const float* noisy = (const float*)d_in[0];
    const float* aux   = (const float*)d_in[1];
    const float* w_map = (const float*)d_in[2];
    const float* b_map = (const float*)d_in[3];
    const float* w_q   = (const float*)d_in[4];
    const float* w_k   = (const float*)d_in[5];
    const float* w_v   = (const float*)d_in[6];
    const float* rel_h = (const float*)d_in[7];
    const float* rel_w = (const float*)d_in[8];
    float* out = (float*)d_out;

    // ws layout (96 MiB): [nv(naux->vmap) 32MiB][kmap 32MiB][qmap 32MiB]
    u16* nv   = (u16*)d_ws;
    u16* kmap = nv   + (size_t)16777216;
    u16* qmap = kmap + (size_t)16777216;

    wconv_kernel<<<1280, 256, 0, stream>>>(w_map, w_q, w_k, w_v);
    // map: [noisy;aux] (K=512) -> nv, relu
    conv2_kernel<0><<<dim3(128, 2, 4), 256, 0, stream>>>(noisy, aux, nullptr, 0, b_map,
                                                         nv, nv, 512, 1.f, 1.f, 1);
    // fused k|q: nv (K=256) -> kmap (scale 1) | qmap (scale 0.125)
    conv2_kernel<1><<<dim3(128, 4, 4), 256, 0, stream>>>(nullptr, nullptr, nv, 131072, nullptr,
                                                         kmap, qmap, 256, 1.f, 0.125f, 0);
    // v: noisy (K=256) -> nv
    conv2_kernel<0><<<dim3(128, 2, 4), 256, 0, stream>>>(noisy, noisy, nullptr, 262144, nullptr,
                                                         nv, nv, 256, 1.f, 1.f, 0);
    attn_kernel<<<dim3(16, 16, 16), 256, 0, stream>>>(qmap, kmap, nv, rel_h, rel_w, out);
}